// Round 1
// baseline (1544.723 us; speedup 1.0000x reference)
//
#include <hip/hip_runtime.h>

#define DTC 0.01f

typedef __attribute__((ext_vector_type(8))) short short8;
typedef __attribute__((ext_vector_type(4))) float floatx4;

#if __has_builtin(__builtin_amdgcn_exp2f)
#define EXP2F(x) __builtin_amdgcn_exp2f(x)
#else
#define EXP2F(x) exp2f(x)
#endif
#if __has_builtin(__builtin_amdgcn_rcpf)
#define RCPF(x) __builtin_amdgcn_rcpf(x)
#else
#define RCPF(x) (1.0f / (x))
#endif

__device__ __forceinline__ unsigned short f2bf(float f) {
    unsigned u = __float_as_uint(f);
    u += 0x7FFFu + ((u >> 16) & 1u);
    return (unsigned short)(u >> 16);
}
__device__ __forceinline__ float sigm(float x) {
    float e = EXP2F(-1.44269504089f * x);
    return RCPF(1.0f + e);
}
__device__ __forceinline__ float tanh_f(float x) {
    float e = EXP2F(2.88539008178f * x);   // e^{2x}
    return 1.0f - 2.0f * RCPF(e + 1.0f);
}

// LDS strides in bf16 elements; byte strides are 16*odd (208, 272) so the 64
// b128 A-frag reads spread uniformly over the 8 bank-chunk positions.
#define U0S 104
#define U1S 136

__global__ __launch_bounds__(256, 1) void lstm_mfma(
    const float* __restrict__ x,    const float* __restrict__ s0,
    const float* __restrict__ W_ih0,const float* __restrict__ W_hh0,
    const float* __restrict__ b_ih0,const float* __restrict__ b_hh0,
    const float* __restrict__ W_ih1,const float* __restrict__ W_hh1,
    const float* __restrict__ b_ih1,const float* __restrict__ b_hh1,
    const float* __restrict__ fc_W, const float* __restrict__ fc_b,
    const int* __restrict__ nsp,    float* __restrict__ out, int B)
{
    // U0: [16 rows m][cols: 0..63 = h_a(bf16), 64..71 = s(bf16), 72..95 = 0]
    // U1: [16 rows m][cols: 0..63 = h_a, 64..127 = h_b]
    __shared__ unsigned short U0[16 * U0S];
    __shared__ unsigned short U1[16 * U1S];

    const int ns   = nsp[0];
    const int tid  = threadIdx.x;
    const int lane = tid & 63;
    const int wave = tid >> 6;
    const int il   = lane & 15;
    const int quad = lane >> 4;
    const int bb   = blockIdx.x * 16;

    float* cal = out + (size_t)B * ns * 8;
    float* res = cal + ns;

    if (blockIdx.x == 0)
        for (int t = tid; t < ns; t += 256) cal[t] = t * DTC;

    for (int i = tid; i < 16 * U0S; i += 256) U0[i] = 0;
    for (int i = tid; i < 16 * U1S; i += 256) U1[i] = 0;

    // ---- register-resident B-fragments (weights constant over time) ----
    // Wave w owns strided n-tiles: gate j lives at cols n = 64*j + 16*w + il,
    // so each wave's MFMA output holds complete (i,f,g,o) quadruples for
    // hidden indices [16w, 16w+16) -> cell update entirely in registers.
    short8 B0[4][3], B1[4][4], BF[2];
    floatx4 bias0[4];
    float bias1[4];
    for (int j = 0; j < 4; ++j) {
        const int n = 64 * j + 16 * wave + il;
        for (int kk = 0; kk < 3; ++kk) {        // G0: K = [h_a(64) | s(8) | 0(24)]
            short8 f;
            #pragma unroll
            for (int jj = 0; jj < 8; ++jj) {
                int k = 32 * kk + 8 * quad + jj;
                float w;
                if (k < 64)      w = W_hh0[n * 64 + k];
                else if (k < 72) w = W_ih0[n * 16 + 8 + (k - 64)];
                else             w = 0.0f;
                f[jj] = (short)f2bf(w);
            }
            B0[j][kk] = f;
        }
        for (int kk = 0; kk < 4; ++kk) {        // G1: K = [h_a(64) | h_b(64)]
            short8 f;
            #pragma unroll
            for (int jj = 0; jj < 8; ++jj) {
                int k = 32 * kk + 8 * quad + jj;
                float w = (k < 64) ? W_ih1[n * 64 + k] : W_hh1[n * 64 + (k - 64)];
                f[jj] = (short)f2bf(w);
            }
            B1[j][kk] = f;
        }
        // fold xin (constant over time) into the layer-0 bias, fp32
        float bcol = b_ih0[n] + b_hh0[n];
        floatx4 bv;
        #pragma unroll
        for (int reg = 0; reg < 4; ++reg) {
            int m = 4 * quad + reg;
            float acc = bcol;
            for (int k = 0; k < 8; ++k)
                acc += x[(bb + m) * 8 + k] * W_ih0[n * 16 + k];
            bv[reg] = acc;
        }
        bias0[j] = bv;
        bias1[j] = b_ih1[n] + b_hh1[n];
    }
    for (int kk = 0; kk < 2; ++kk) {            // FC head: B[k][n] = fc_W[n][k], n<8
        short8 f;
        #pragma unroll
        for (int jj = 0; jj < 8; ++jj) {
            int k = 32 * kk + 8 * quad + jj;
            float w = (il < 8) ? fc_W[il * 64 + k] : 0.0f;
            f[jj] = (short)f2bf(w);
        }
        BF[kk] = f;
    }
    const float fcb = (il < 8) ? fc_b[il] : 0.0f;

    // ---- state ----
    float cA[4] = {0, 0, 0, 0}, cB[4] = {0, 0, 0, 0};
    float s_reg[4];
    #pragma unroll
    for (int reg = 0; reg < 4; ++reg) {
        int m = 4 * quad + reg;
        s_reg[reg] = (il < 8) ? s0[(bb + m) * 8 + il] : 0.0f;
    }
    if (wave == 0 && il < 8) {
        #pragma unroll
        for (int reg = 0; reg < 4; ++reg)
            U0[(4 * quad + reg) * U0S + 64 + il] = f2bf(s_reg[reg]);
    }
    __syncthreads();

    const int iidx = 16 * wave + il;   // hidden index owned for cell updates

    #pragma unroll 1
    for (int t = 0; t < ns; ++t) {
        // phase 1: all A-frag reads of state from the previous step
        short8 a00 = *(const short8*)&U0[il * U0S + 0  + 8 * quad];
        short8 a01 = *(const short8*)&U0[il * U0S + 32 + 8 * quad];
        short8 a02 = *(const short8*)&U0[il * U0S + 64 + 8 * quad];
        short8 a12 = *(const short8*)&U1[il * U1S + 64 + 8 * quad];  // h_b(t-1)
        short8 a13 = *(const short8*)&U1[il * U1S + 96 + 8 * quad];
        __syncthreads();   // A: reads done before anyone overwrites

        // layer-0 gates
        floatx4 g0[4];
        #pragma unroll
        for (int j = 0; j < 4; ++j) {
            floatx4 acc = bias0[j];
            acc = __builtin_amdgcn_mfma_f32_16x16x32_bf16(a00, B0[j][0], acc, 0, 0, 0);
            acc = __builtin_amdgcn_mfma_f32_16x16x32_bf16(a01, B0[j][1], acc, 0, 0, 0);
            acc = __builtin_amdgcn_mfma_f32_16x16x32_bf16(a02, B0[j][2], acc, 0, 0, 0);
            g0[j] = acc;
        }
        #pragma unroll
        for (int reg = 0; reg < 4; ++reg) {
            float ig = sigm(g0[0][reg]);
            float fg = sigm(g0[1][reg]);
            float gg = tanh_f(g0[2][reg]);
            float og = sigm(g0[3][reg]);
            float c  = fg * cA[reg] + ig * gg;
            cA[reg]  = c;
            unsigned short hb = f2bf(og * tanh_f(c));
            int m = 4 * quad + reg;
            U0[m * U0S + iidx] = hb;          // h_a for next step's G0
            U1[m * U1S + iidx] = hb;          // h_a for this step's G1
        }
        __syncthreads();   // B

        short8 a10 = *(const short8*)&U1[il * U1S + 0  + 8 * quad];  // h_a(t)
        short8 a11 = *(const short8*)&U1[il * U1S + 32 + 8 * quad];
        floatx4 g1[4];
        #pragma unroll
        for (int j = 0; j < 4; ++j) {
            floatx4 acc = {bias1[j], bias1[j], bias1[j], bias1[j]};
            acc = __builtin_amdgcn_mfma_f32_16x16x32_bf16(a10, B1[j][0], acc, 0, 0, 0);
            acc = __builtin_amdgcn_mfma_f32_16x16x32_bf16(a11, B1[j][1], acc, 0, 0, 0);
            acc = __builtin_amdgcn_mfma_f32_16x16x32_bf16(a12, B1[j][2], acc, 0, 0, 0);
            acc = __builtin_amdgcn_mfma_f32_16x16x32_bf16(a13, B1[j][3], acc, 0, 0, 0);
            g1[j] = acc;
        }
        #pragma unroll
        for (int reg = 0; reg < 4; ++reg) {
            float ig = sigm(g1[0][reg]);
            float fg = sigm(g1[1][reg]);
            float gg = tanh_f(g1[2][reg]);
            float og = sigm(g1[3][reg]);
            float c  = fg * cB[reg] + ig * gg;
            cB[reg]  = c;
            int m = 4 * quad + reg;
            U1[m * U1S + 64 + iidx] = f2bf(og * tanh_f(c));  // h_b(t)
        }
        __syncthreads();   // C

        short8 af0 = *(const short8*)&U1[il * U1S + 64 + 8 * quad];  // h_b(t)
        short8 af1 = *(const short8*)&U1[il * U1S + 96 + 8 * quad];
        floatx4 so = {fcb, fcb, fcb, fcb};
        so = __builtin_amdgcn_mfma_f32_16x16x32_bf16(af0, BF[0], so, 0, 0, 0);
        so = __builtin_amdgcn_mfma_f32_16x16x32_bf16(af1, BF[1], so, 0, 0, 0);

        #pragma unroll
        for (int reg = 0; reg < 4; ++reg) s_reg[reg] += so[reg] * DTC;

        if (wave == 0 && il < 8) {
            #pragma unroll
            for (int reg = 0; reg < 4; ++reg) {
                int m = 4 * quad + reg;
                U0[m * U0S + 64 + il] = f2bf(s_reg[reg]);
                size_t o = ((size_t)(bb + m) * ns + t) * 8 + il;
                out[o] = s_reg[reg];
                res[o] = so[reg];
            }
        }
        __syncthreads();   // D: s in U0 stable before next step's reads
    }
}

extern "C" void kernel_launch(void* const* d_in, const int* in_sizes, int n_in,
                              void* d_out, int out_size, void* d_ws, size_t ws_size,
                              hipStream_t stream) {
    const float* x     = (const float*)d_in[0];
    const float* s0    = (const float*)d_in[1];
    const float* W_ih0 = (const float*)d_in[2];
    const float* W_hh0 = (const float*)d_in[3];
    const float* b_ih0 = (const float*)d_in[4];
    const float* b_hh0 = (const float*)d_in[5];
    const float* W_ih1 = (const float*)d_in[6];
    const float* W_hh1 = (const float*)d_in[7];
    const float* b_ih1 = (const float*)d_in[8];
    const float* b_hh1 = (const float*)d_in[9];
    const float* fc_W  = (const float*)d_in[10];
    const float* fc_b  = (const float*)d_in[11];
    const int*   nsp   = (const int*)d_in[12];
    (void)d_ws; (void)ws_size; (void)n_in; (void)out_size;
    int B = in_sizes[0] / 8;          // 4096
    dim3 grid(B / 16), block(256);    // 256 blocks -> 1 per CU
    hipLaunchKernelGGL(lstm_mfma, grid, block, 0, stream,
        x, s0, W_ih0, W_hh0, b_ih0, b_hh0, W_ih1, W_hh1, b_ih1, b_hh1,
        fc_W, fc_b, nsp, (float*)d_out, B);
}